// Round 5
// baseline (249.764 us; speedup 1.0000x reference)
//
#include <hip/hip_runtime.h>
#include <hip/hip_bf16.h>

#define HIDDEN 128
#define NEDGES 800000
#define TILE_M 32
#define KDIM 384
#define NKSTEP 12                 // 384 / 32
#define NTILES (NEDGES / TILE_M)  // 25000

typedef __attribute__((ext_vector_type(8))) short short8;
typedef __attribute__((ext_vector_type(4))) float f32x4;
typedef __attribute__((ext_vector_type(4))) float f4;
typedef __attribute__((ext_vector_type(4))) int   i32x4;

__device__ __forceinline__ unsigned short f2bf(float x) {
    union { __hip_bfloat16 b; unsigned short u; } c;
    c.b = __float2bfloat16(x);
    return c.u;
}

// Pack W (384x128 f32) into bf16 MFMA B-fragment order:
// frag = ks*8 + nf; lane holds col n = nf*16 + (lane&15),
// k = ks*32 + (lane>>4)*8 + i, i=0..7 contiguous (16B/lane).
__global__ void __launch_bounds__(256) pack_w_kernel(const float* __restrict__ W,
                                                     unsigned short* __restrict__ Wp) {
    int t = blockIdx.x * 256 + threadIdx.x;
    if (t >= 96 * 64) return;
    int lane = t & 63;
    int frag = t >> 6;
    int ks = frag >> 3, nf = frag & 7;
    int hi = lane >> 4, lo = lane & 15;
    short8 g;
#pragma unroll
    for (int i = 0; i < 8; ++i) {
        int k = ks * 32 + hi * 8 + i;
        int n = nf * 16 + lo;
        g[i] = (short)f2bf(W[k * HIDDEN + n]);
    }
    *(short8*)(Wp + (size_t)t * 8) = g;
}

// convert 2 f4 -> short8 and write to swizzled LDS granule
#define CVT8(ldsrow_, u_, v_, col8_, swz_)                                   \
    do {                                                                     \
        short8 pk;                                                           \
        pk[0] = (short)f2bf((u_)[0]); pk[1] = (short)f2bf((u_)[1]);          \
        pk[2] = (short)f2bf((u_)[2]); pk[3] = (short)f2bf((u_)[3]);          \
        pk[4] = (short)f2bf((v_)[0]); pk[5] = (short)f2bf((v_)[1]);          \
        pk[6] = (short)f2bf((v_)[2]); pk[7] = (short)f2bf((v_)[3]);          \
        *(short8*)((ldsrow_) + (size_t)(((col8_) ^ (swz_)) * 8)) = pk;       \
    } while (0)

__global__ void __launch_bounds__(256, 2) edge_gemm_kernel(
    const float* __restrict__ nef,
    const float* __restrict__ dist,
    const int*   __restrict__ srcs,
    const int*   __restrict__ dsts,
    const unsigned short* __restrict__ Wp,
    const float* __restrict__ bias,
    float*       __restrict__ out)
{
    __shared__ __align__(16) unsigned short A_lds[2][TILE_M * KDIM]; // 2 x 24 KiB

    const int tid  = threadIdx.x;
    const int lane = tid & 63;
    const int wid  = tid >> 6;
    const int lo   = lane & 15;
    const int hi   = lane >> 4;

    const float bv0 = bias[wid * 32 + lo];
    const float bv1 = bias[wid * 32 + 16 + lo];

    const int eg  = tid >> 3;   // edge row in tile
    const int lt  = tid & 7;    // 8 threads per edge row
    const int swz = eg & 7;

    // ---- B fragments: load once, PIN in VGPRs for the whole kernel ----
    i32x4 B[NKSTEP][2];
#pragma unroll
    for (int ks = 0; ks < NKSTEP; ++ks) {
#pragma unroll
        for (int nf = 0; nf < 2; ++nf) {
            int frag = ks * 8 + wid * 2 + nf;
            B[ks][nf] = *(const i32x4*)(Wp + ((size_t)frag * 64 + lane) * 8);
        }
    }

    int tile = blockIdx.x;
    const int stride = gridDim.x;
    if (tile >= NTILES) return;

    // ---- prologue: indices for tile, tile+stride; gathers for tile ----
    int e0 = tile * TILE_M + eg;
    int s_cur = srcs[e0], d_cur = dsts[e0];
    int s_nxt = 0, d_nxt = 0;
    {
        int t1 = tile + stride;
        if (t1 < NTILES) { int e1 = t1 * TILE_M + eg; s_nxt = srcs[e1]; d_nxt = dsts[e1]; }
    }

    // named staging registers — must never spill (rule #20)
    f4 r0, r1, r2, r3, r4, r5, r6, r7, r8, r9, r10, r11;
    {
        const f4* srow = (const f4*)nef  + (size_t)s_cur * 32;
        const f4* drow = (const f4*)nef  + (size_t)d_cur * 32;
        const f4* frow = (const f4*)dist + (size_t)e0 * 32;
        const int g0 = 2 * lt, g1 = 2 * (lt + 8);
        r0 = srow[g0]; r1 = srow[g0 + 1]; r2 = srow[g1]; r3 = srow[g1 + 1];
        r4 = drow[g0]; r5 = drow[g0 + 1]; r6 = drow[g1]; r7 = drow[g1 + 1];
        r8  = __builtin_nontemporal_load(frow + g0);
        r9  = __builtin_nontemporal_load(frow + g0 + 1);
        r10 = __builtin_nontemporal_load(frow + g1);
        r11 = __builtin_nontemporal_load(frow + g1 + 1);
    }

    int p = 0;
    while (tile < NTILES) {
        // pin B: zero-instruction asm makes values loop-carried in VGPRs —
        // compiler cannot sink/rematerialize the loads into the loop, so the
        // MFMA phase has NO VMEM reads and the gathers below stay in flight.
#pragma unroll
        for (int ks = 0; ks < NKSTEP; ++ks) {
            asm volatile("" : "+v"(B[ks][0]), "+v"(B[ks][1]));
        }

        // ---- convert + write LDS buf[p] (waits on r arrival here) ----
        unsigned short* ldsrow = A_lds[p] + eg * KDIM;
        CVT8(ldsrow, r0, r1, lt,            swz);
        CVT8(ldsrow, r2, r3, lt + 8,        swz);
        CVT8(ldsrow, r4, r5, 16 + lt,       swz);
        CVT8(ldsrow, r6, r7, 16 + lt + 8,   swz);
        CVT8(ldsrow, r8, r9, 32 + lt,       swz);
        CVT8(ldsrow, r10, r11, 32 + lt + 8, swz);

        // single barrier per tile: makes buf[p] visible; buf[p^1] writes vs
        // buf[p] reads are disjoint, and waves are <=1 barrier apart -> safe.
        __syncthreads();

        // ---- issue NEXT tile's gathers: in flight across MFMA + epilogue ----
        const int t_next = tile + stride;
        if (t_next < NTILES) {
            int en = t_next * TILE_M + eg;
            const f4* srow = (const f4*)nef  + (size_t)s_nxt * 32;
            const f4* drow = (const f4*)nef  + (size_t)d_nxt * 32;
            const f4* frow = (const f4*)dist + (size_t)en * 32;
            const int g0 = 2 * lt, g1 = 2 * (lt + 8);
            r0 = srow[g0]; r1 = srow[g0 + 1]; r2 = srow[g1]; r3 = srow[g1 + 1];
            r4 = drow[g0]; r5 = drow[g0 + 1]; r6 = drow[g1]; r7 = drow[g1 + 1];
            r8  = __builtin_nontemporal_load(frow + g0);
            r9  = __builtin_nontemporal_load(frow + g0 + 1);
            r10 = __builtin_nontemporal_load(frow + g1);
            r11 = __builtin_nontemporal_load(frow + g1 + 1);
            int t2 = t_next + stride;
            if (t2 < NTILES) { int e2 = t2 * TILE_M + eg; s_nxt = srcs[e2]; d_nxt = dsts[e2]; }
        }

        // ---- compute: A from LDS buf[p], B from pinned registers ----
        f32x4 acc00 = {0.f, 0.f, 0.f, 0.f};
        f32x4 acc01 = {0.f, 0.f, 0.f, 0.f};
        f32x4 acc10 = {0.f, 0.f, 0.f, 0.f};
        f32x4 acc11 = {0.f, 0.f, 0.f, 0.f};
        const unsigned short* abase = A_lds[p];
#pragma unroll
        for (int ks = 0; ks < NKSTEP; ++ks) {
            const int c8 = ks * 4 + hi;
            short8 a0 = *(const short8*)(abase + lo * KDIM + ((c8 ^ (lo & 7)) * 8));
            short8 a1 = *(const short8*)(abase + (16 + lo) * KDIM + ((c8 ^ (lo & 7)) * 8));
            short8 b0 = __builtin_bit_cast(short8, B[ks][0]);
            short8 b1 = __builtin_bit_cast(short8, B[ks][1]);
            acc00 = __builtin_amdgcn_mfma_f32_16x16x32_bf16(a0, b0, acc00, 0, 0, 0);
            acc01 = __builtin_amdgcn_mfma_f32_16x16x32_bf16(a0, b1, acc01, 0, 0, 0);
            acc10 = __builtin_amdgcn_mfma_f32_16x16x32_bf16(a1, b0, acc10, 0, 0, 0);
            acc11 = __builtin_amdgcn_mfma_f32_16x16x32_bf16(a1, b1, acc11, 0, 0, 0);
        }

        // ---- epilogue: +bias, relu, nt store (never re-read) ----
#pragma unroll
        for (int rr = 0; rr < 4; ++rr) {
            const int row0 = tile * TILE_M + hi * 4 + rr;
            const int row1 = row0 + 16;
            const int col0 = wid * 32 + lo;
            const int col1 = col0 + 16;
            float v00 = acc00[rr] + bv0;
            float v01 = acc01[rr] + bv1;
            float v10 = acc10[rr] + bv0;
            float v11 = acc11[rr] + bv1;
            __builtin_nontemporal_store(v00 > 0.f ? v00 : 0.f, &out[(size_t)row0 * HIDDEN + col0]);
            __builtin_nontemporal_store(v01 > 0.f ? v01 : 0.f, &out[(size_t)row0 * HIDDEN + col1]);
            __builtin_nontemporal_store(v10 > 0.f ? v10 : 0.f, &out[(size_t)row1 * HIDDEN + col0]);
            __builtin_nontemporal_store(v11 > 0.f ? v11 : 0.f, &out[(size_t)row1 * HIDDEN + col1]);
        }

        tile = t_next;
        p ^= 1;
    }
}

extern "C" void kernel_launch(void* const* d_in, const int* in_sizes, int n_in,
                              void* d_out, int out_size, void* d_ws, size_t ws_size,
                              hipStream_t stream) {
    const float* nef  = (const float*)d_in[0];
    const float* dist = (const float*)d_in[1];
    const int*   srcs = (const int*)d_in[2];
    const int*   dsts = (const int*)d_in[3];
    const float* W    = (const float*)d_in[4];
    const float* bias = (const float*)d_in[5];
    float* out = (float*)d_out;
    unsigned short* Wp = (unsigned short*)d_ws;

    hipLaunchKernelGGL(pack_w_kernel, dim3(24), dim3(256), 0, stream, W, Wp);
    hipLaunchKernelGGL(edge_gemm_kernel, dim3(512), dim3(256), 0, stream,
                       nef, dist, srcs, dsts, Wp, bias, out);
}